// Round 7
// baseline (284.042 us; speedup 1.0000x reference)
//
#include <hip/hip_runtime.h>
#include <hip/hip_bf16.h>
#include <cstdint>
#include <cstddef>

using bf16x8 = __attribute__((ext_vector_type(8))) short;
using f32x4  = __attribute__((ext_vector_type(4))) float;

#define GAS __attribute__((address_space(1)))
#define LAS __attribute__((address_space(3)))

static constexpr int Tdim = 4096;
static constexpr int Ddim = 2048;
static constexpr int N1   = 6144;   // 3*Ddim

__device__ __forceinline__ unsigned short f32_to_bf16(float f) {
    union { float f; unsigned u; } v; v.f = f;
    return (unsigned short)((v.u + 0x7FFFu + ((v.u >> 16) & 1u)) >> 16);
}
__device__ __forceinline__ float bflo(unsigned u){ union{unsigned x;float f;}v; v.x = u << 16;        return v.f; }
__device__ __forceinline__ float bfhi(unsigned u){ union{unsigned x;float f;}v; v.x = u & 0xFFFF0000u; return v.f; }

// ---------------- fused f32 -> bf16 conversion for x, Wq, Wk, Wv ----------------
__global__ __launch_bounds__(256) void cvt_all(const float* __restrict__ x,
                                               const float* __restrict__ Wq,
                                               const float* __restrict__ Wk,
                                               const float* __restrict__ Wv,
                                               unsigned short* __restrict__ xb,
                                               unsigned short* __restrict__ Wb) {
    constexpr int NX = (Tdim * Ddim) / 4;
    constexpr int NWm = (Ddim * Ddim) / 4;
    const int i0 = blockIdx.x * blockDim.x + threadIdx.x;
    const int stride = gridDim.x * blockDim.x;
    for (int i = i0; i < NX + 3 * NWm; i += stride) {
        const float* s; unsigned short* d; int j;
        if (i < NX)            { s = x;  d = xb;                            j = i; }
        else if (i < NX+NWm)   { s = Wq; d = Wb;                            j = i - NX; }
        else if (i < NX+2*NWm) { s = Wk; d = Wb + (size_t)Ddim*Ddim;        j = i - NX - NWm; }
        else                   { s = Wv; d = Wb + 2*(size_t)Ddim*Ddim;      j = i - NX - 2*NWm; }
        float4 f = ((const float4*)s)[j];
        ushort4 o;
        o.x = f32_to_bf16(f.x); o.y = f32_to_bf16(f.y);
        o.z = f32_to_bf16(f.z); o.w = f32_to_bf16(f.w);
        ((ushort4*)d)[j] = o;
    }
}

__device__ __forceinline__ void gload16(const void* g, void* l) {
    __builtin_amdgcn_global_load_lds((GAS void*)g, (LAS void*)l, 16, 0, 0);
}

// T2 swizzle for 64B-stride rows (involution on byte bits [5:4]): 16 consecutive
// rows x 4 slots -> 8 bank-groups x 2 lanes = conflict-free (verified 0 in R2-R6).
__device__ __forceinline__ int swz(int r) { return ((r >> 1) & 3) << 4; }

// ================= k1: 256x256 kh-progressive 4-phase pipeline =================
// BK=64 split into K-halves; LDS buffer = A-kh0|A-kh1|B-kh0|B-kh1, each 16KB
// ([256 rows][64B], swizzled). Phases P1/P2 consume kh0, P3/P4 consume kh1;
// each phase stages exactly one kh-region of tile t+1 (FIFO order Akh0,Bkh0,
// Akh1,Bkh1) -> every load has 4 phases of slack; vmcnt(4) only at P1/P3
// (never 0 mid-loop); barriers only at P1/P3 entry.
static constexpr int LDS_K1 = 131072;    // 2 buffers x 64KB

__device__ __forceinline__ void pipe256(const unsigned short* __restrict__ Ag, int lda,
                                        const unsigned short* __restrict__ Bg, int ldb,
                                        int row0, int col0, int nt,
                                        char* lds, f32x4 acc[8][4]) {
    const int tid = threadIdx.x, wave = tid >> 6, lane = tid & 63;
    const int wr = wave >> 2, wc = wave & 3;   // wave-tile 128x64 (2M x 4N)

    // staging: thread -> row gr of gang g (g*128+gr), 16B slot; src pre-swizzled
    const int gr  = tid >> 2;
    const int gcs = (tid & 3) << 4;
    const char* pA[2]; const char* pB[2];
    #pragma unroll
    for (int g = 0; g < 2; ++g) {
        int r = g * 128 + gr;
        pA[g] = (const char*)Ag + (size_t)(row0 + r) * (size_t)(lda * 2) + (gcs ^ swz(r));
        pB[g] = (const char*)Bg + (size_t)(col0 + r) * (size_t)(ldb * 2) + (gcs ^ swz(r));
    }
    const int wv = wave * 1024;                // wave-uniform LDS base within gang

    const int fr = lane & 15, cB = (lane >> 4) << 4;
    int offA[8], offB[4];
    #pragma unroll
    for (int m = 0; m < 8; ++m) { int r = wr*128 + m*16 + fr; offA[m] = r*64 + (cB ^ swz(r)); }
    #pragma unroll
    for (int n = 0; n < 4; ++n) { int r = wc*64  + n*16 + fr; offB[n] = 32768 + r*64 + (cB ^ swz(r)); }

    #pragma unroll
    for (int m = 0; m < 8; ++m)
        #pragma unroll
        for (int n = 0; n < 4; ++n)
            #pragma unroll
            for (int q = 0; q < 4; ++q) acc[m][n][q] = 0.f;

    // prologue: stage tile 0 into buf0 in consumption order Akh0,Bkh0,Akh1,Bkh1
    gload16(pA[0],      lds + wv);           gload16(pA[1],      lds +  8192 + wv);
    gload16(pB[0],      lds + 32768 + wv);   gload16(pB[1],      lds + 40960 + wv);
    gload16(pA[0] + 64, lds + 16384 + wv);   gload16(pA[1] + 64, lds + 24576 + wv);
    gload16(pB[0] + 64, lds + 49152 + wv);   gload16(pB[1] + 64, lds + 57344 + wv);

    for (int t = 0; t < nt; ++t) {
        const char* buf = lds + (t & 1) * 65536;
        char* obuf      = lds + ((t + 1) & 1) * 65536;
        const bool st   = (t + 1 < nt);
        const size_t ko = (size_t)(t + 1) * 128;
        bf16x8 a[4], b[4];

        // ---- P1: kh0, m0-3 | stage Akh0(t+1) ----
        asm volatile("s_waitcnt vmcnt(4)" ::: "memory");   // kh0(t) landed (4 newest = kh1(t))
        __builtin_amdgcn_s_barrier();
        __builtin_amdgcn_sched_barrier(0);
        #pragma unroll
        for (int m = 0; m < 4; ++m) a[m] = *(const bf16x8*)(buf + offA[m]);
        #pragma unroll
        for (int n = 0; n < 4; ++n) b[n] = *(const bf16x8*)(buf + offB[n]);
        if (st) { gload16(pA[0] + ko, obuf + wv); gload16(pA[1] + ko, obuf + 8192 + wv); }
        __builtin_amdgcn_s_setprio(1);
        #pragma unroll
        for (int m = 0; m < 4; ++m)
            #pragma unroll
            for (int n = 0; n < 4; ++n)
                acc[m][n] = __builtin_amdgcn_mfma_f32_16x16x32_bf16(a[m], b[n], acc[m][n], 0, 0, 0);
        __builtin_amdgcn_s_setprio(0);
        __builtin_amdgcn_sched_barrier(0);

        // ---- P2: kh0, m4-7 (reuse b) | stage Bkh0(t+1) ----
        #pragma unroll
        for (int m = 0; m < 4; ++m) a[m] = *(const bf16x8*)(buf + offA[4 + m]);
        if (st) { gload16(pB[0] + ko, obuf + 32768 + wv); gload16(pB[1] + ko, obuf + 40960 + wv); }
        __builtin_amdgcn_s_setprio(1);
        #pragma unroll
        for (int m = 0; m < 4; ++m)
            #pragma unroll
            for (int n = 0; n < 4; ++n)
                acc[4 + m][n] = __builtin_amdgcn_mfma_f32_16x16x32_bf16(a[m], b[n], acc[4 + m][n], 0, 0, 0);
        __builtin_amdgcn_s_setprio(0);
        __builtin_amdgcn_sched_barrier(0);

        // ---- P3: kh1, m0-3 | stage Akh1(t+1) ----
        if (st) asm volatile("s_waitcnt vmcnt(4)" ::: "memory"); // kh1(t) landed (4 newest = kh0(t+1))
        else    asm volatile("s_waitcnt vmcnt(0)" ::: "memory");
        __builtin_amdgcn_s_barrier();
        __builtin_amdgcn_sched_barrier(0);
        #pragma unroll
        for (int m = 0; m < 4; ++m) a[m] = *(const bf16x8*)(buf + 16384 + offA[m]);
        #pragma unroll
        for (int n = 0; n < 4; ++n) b[n] = *(const bf16x8*)(buf + 16384 + offB[n]);
        if (st) { gload16(pA[0] + 64 + ko, obuf + 16384 + wv); gload16(pA[1] + 64 + ko, obuf + 24576 + wv); }
        __builtin_amdgcn_s_setprio(1);
        #pragma unroll
        for (int m = 0; m < 4; ++m)
            #pragma unroll
            for (int n = 0; n < 4; ++n)
                acc[m][n] = __builtin_amdgcn_mfma_f32_16x16x32_bf16(a[m], b[n], acc[m][n], 0, 0, 0);
        __builtin_amdgcn_s_setprio(0);
        __builtin_amdgcn_sched_barrier(0);

        // ---- P4: kh1, m4-7 (reuse b) | stage Bkh1(t+1) ----
        #pragma unroll
        for (int m = 0; m < 4; ++m) a[m] = *(const bf16x8*)(buf + 16384 + offA[4 + m]);
        if (st) { gload16(pB[0] + 64 + ko, obuf + 49152 + wv); gload16(pB[1] + 64 + ko, obuf + 57344 + wv); }
        __builtin_amdgcn_s_setprio(1);
        #pragma unroll
        for (int m = 0; m < 4; ++m)
            #pragma unroll
            for (int n = 0; n < 4; ++n)
                acc[4 + m][n] = __builtin_amdgcn_mfma_f32_16x16x32_bf16(a[m], b[n], acc[4 + m][n], 0, 0, 0);
        __builtin_amdgcn_s_setprio(0);
        __builtin_amdgcn_sched_barrier(0);
    }
}

// ---------------- K1: fused QKV projection + sigmoid epilogue (256x256, 8 waves) ----------------
__global__ __launch_bounds__(512, 2) void k1_proj(const unsigned short* __restrict__ xb,
                                                  const unsigned short* __restrict__ Wb,
                                                  unsigned short* __restrict__ qkv) {
    extern __shared__ __align__(16) char lds[];
    const int bj = blockIdx.x, bi = blockIdx.y;   // natural 2D grid: bj fastest (L2-good, R3-proven)
    f32x4 acc[8][4];
    pipe256(xb, Ddim, Wb, Ddim, bi * 256, bj * 256, Ddim / 64, lds, acc);
    const int lane = threadIdx.x & 63, wave = threadIdx.x >> 6;
    const int wr = wave >> 2, wc = wave & 3;
    const int er = (lane >> 4) * 4, ec = lane & 15;
    #pragma unroll
    for (int n = 0; n < 4; ++n) {
        const int c = bj*256 + wc*64 + n*16 + ec;
        const bool isQK = (c < 2*Ddim);
        const int ihalf = (c & (Ddim-1)) >> 1;
        float theta = 0.0f;
        if (isQK && ihalf < 2) theta = powf(10000.0f, -2.0f*(float)ihalf);
        #pragma unroll
        for (int m = 0; m < 8; ++m) {
            #pragma unroll
            for (int jj = 0; jj < 4; ++jj) {
                const int t = bi*256 + wr*128 + m*16 + er + jj;
                float v = acc[m][n][jj];
                float ov;
                if (isQK) {
                    float cs = 1.0f;  // exact for ihalf>=2 (ang<=4e-13 -> cos+sin==1.0f)
                    if (ihalf < 2) { float ang = (float)t * theta; cs = cosf(ang) + sinf(ang); }
                    float z = v * cs * (1.0f/2048.0f);
                    ov = 1.0f / (1.0f + expf(-z));
                } else {
                    ov = v;
                }
                qkv[(size_t)t * N1 + c] = f32_to_bf16(ov);
            }
        }
    }
}

// ================= 128-tile ring-3 pipeline (k2/k3, R3-proven) =================
template<int TBM, int TBN, int NW, int MR>
__device__ __forceinline__ void pipe_gemm(const unsigned short* __restrict__ Ag, int lda,
                                          const unsigned short* __restrict__ Bg, int ldb,
                                          int row0, int col0, int nt,
                                          char* lds, f32x4 acc[MR][4]) {
    constexpr int WCOL   = TBN / 64;
    constexpr int ISSUES = (TBM + TBN) / (NW * 16);
    constexpr int BUF    = (TBM + TBN) * 64;
    const int tid = threadIdx.x, wave = tid >> 6, lane = tid & 63;
    const int wr = wave / WCOL, wc = wave % WCOL;

    const char* gp[ISSUES]; int lo[ISSUES];
    #pragma unroll
    for (int i = 0; i < ISSUES; ++i) {
        int o = i * (NW * 1024) + wave * 1024 + (lane << 4);
        lo[i] = i * (NW * 1024) + wave * 1024;
        if (o < TBM * 64) {
            int r = o >> 6, cp = o & 63;
            gp[i] = (const char*)Ag + (size_t)(row0 + r) * (size_t)lda * 2 + (cp ^ swz(r));
        } else {
            int o2 = o - TBM * 64; int r = o2 >> 6, cp = o2 & 63;
            gp[i] = (const char*)Bg + (size_t)(col0 + r) * (size_t)ldb * 2 + (cp ^ swz(r));
        }
    }
    const int fr = lane & 15, fkB = (lane >> 4) << 4;
    int offA[MR], offB[4];
    #pragma unroll
    for (int m = 0; m < MR; ++m) { int r = wr*(MR*16) + m*16 + fr; offA[m] = r*64 + (fkB ^ swz(r)); }
    #pragma unroll
    for (int n = 0; n < 4; ++n)  { int r = wc*64 + n*16 + fr; offB[n] = TBM*64 + r*64 + (fkB ^ swz(r)); }

    #pragma unroll
    for (int m = 0; m < MR; ++m)
        #pragma unroll
        for (int n = 0; n < 4; ++n)
            #pragma unroll
            for (int q = 0; q < 4; ++q) acc[m][n][q] = 0.0f;

    #pragma unroll
    for (int tt = 0; tt < 2; ++tt) {
        char* dst = lds + tt * BUF;
        #pragma unroll
        for (int i = 0; i < ISSUES; ++i) gload16(gp[i] + (size_t)tt * 64, dst + lo[i]);
    }
    asm volatile("s_waitcnt vmcnt(%0)" :: "n"(ISSUES) : "memory");
    __builtin_amdgcn_s_barrier();
    __builtin_amdgcn_sched_barrier(0);

    int cur = 0, stg = 2 * BUF;
    for (int t = 0; t < nt; ++t) {
        const char* buf = lds + cur;
        bf16x8 af[MR], bq[4];
        #pragma unroll
        for (int m = 0; m < MR; ++m) af[m] = *(const bf16x8*)(buf + offA[m]);
        #pragma unroll
        for (int n = 0; n < 4; ++n) bq[n] = *(const bf16x8*)(buf + offB[n]);
        if (t + 2 < nt) {
            char* dst = lds + stg;
            const size_t ko = (size_t)(t + 2) * 64;
            #pragma unroll
            for (int i = 0; i < ISSUES; ++i) gload16(gp[i] + ko, dst + lo[i]);
        }
        __builtin_amdgcn_s_setprio(1);
        #pragma unroll
        for (int m = 0; m < MR; ++m)
            #pragma unroll
            for (int n = 0; n < 4; ++n)
                acc[m][n] = __builtin_amdgcn_mfma_f32_16x16x32_bf16(af[m], bq[n], acc[m][n], 0, 0, 0);
        __builtin_amdgcn_s_setprio(0);
        __builtin_amdgcn_sched_barrier(0);
        if (t + 1 < nt) {
            if (t + 3 <= nt) asm volatile("s_waitcnt vmcnt(%0)" :: "n"(ISSUES) : "memory");
            else             asm volatile("s_waitcnt vmcnt(0)" ::: "memory");
            __builtin_amdgcn_s_barrier();
            __builtin_amdgcn_sched_barrier(0);
        }
        cur = (cur == 2*BUF) ? 0 : cur + BUF;
        stg = (stg == 2*BUF) ? 0 : stg + BUF;
    }
}

static constexpr int LDS_K2 = 3 * (128 + 128) * 64;  // 49152 B

// ---------------- K1b: transpose V -> vT [2048][4096] ----------------
__global__ __launch_bounds__(256) void k1b_trans(const unsigned short* __restrict__ qkv,
                                                 unsigned short* __restrict__ vT) {
    __shared__ unsigned short tile[64][65];
    const int tc = blockIdx.x, tr = blockIdx.y;
    const int x = threadIdx.x & 63, y0 = threadIdx.x >> 6;
    #pragma unroll
    for (int r = 0; r < 64; r += 4) {
        const int row = r + y0;
        tile[row][x] = qkv[(size_t)(tr*64 + row) * N1 + 2*Ddim + tc*64 + x];
    }
    __syncthreads();
    #pragma unroll
    for (int r = 0; r < 64; r += 4) {
        const int row = r + y0;
        vT[(size_t)(tc*64 + row) * Tdim + tr*64 + x] = tile[x][row];
    }
}

// ---------------- K2: A = query @ key^T, lower-tri 128x128 blocks (528) ----------------
// Natural block order (no XCD swizzle): consecutive p share bi -> per-XCD B-panel
// footprint stays small (R6 showed chunked swizzle thrashes L2: FETCH 107->202MB).
__global__ __launch_bounds__(256, 3) void k2_qk(const unsigned short* __restrict__ qkv,
                                                unsigned short* __restrict__ Am) {
    extern __shared__ __align__(16) char lds[];
    const int p = blockIdx.x;
    int bi = (int)((sqrtf(8.0f*(float)p + 1.0f) - 1.0f) * 0.5f);
    while ((bi+1)*(bi+2)/2 <= p) ++bi;
    while (bi*(bi+1)/2 > p) --bi;
    const int bj = p - bi*(bi+1)/2;
    f32x4 acc[4][4];
    pipe_gemm<128, 128, 4, 4>(qkv, N1, qkv + Ddim, N1, bi*128, bj*128, Ddim/32, lds, acc);
    const int lane = threadIdx.x & 63, wave = threadIdx.x >> 6;
    const int wr = wave >> 1, wc = wave & 1;
    const int er = (lane >> 4) * 4, ec = lane & 15;
    #pragma unroll
    for (int n = 0; n < 4; ++n) {
        const int s = bj*128 + wc*64 + n*16 + ec;
        #pragma unroll
        for (int m = 0; m < 4; ++m)
            #pragma unroll
            for (int jj = 0; jj < 4; ++jj) {
                const int t = bi*128 + wr*64 + m*16 + er + jj;
                float v = (s <= t) ? acc[m][n][jj] : 0.0f;
                Am[(size_t)t * Tdim + s] = f32_to_bf16(v);
            }
    }
}

// ---------------- K2b: rden[t] = 1 / sum_{s<=t} A[t][s] ----------------
__global__ __launch_bounds__(256) void k2b_den(const unsigned short* __restrict__ Am,
                                               float* __restrict__ rden) {
    const int t = blockIdx.x;
    const int lim = ((t >> 7) + 1) << 7;
    const unsigned short* row = Am + (size_t)t * Tdim;
    float s = 0.0f;
    for (int idx = threadIdx.x * 8; idx < lim; idx += 2048) {
        uint4 u = *(const uint4*)(row + idx);
        s += bflo(u.x) + bfhi(u.x) + bflo(u.y) + bfhi(u.y)
           + bflo(u.z) + bfhi(u.z) + bflo(u.w) + bfhi(u.w);
    }
    #pragma unroll
    for (int off = 32; off > 0; off >>= 1) s += __shfl_down(s, off, 64);
    __shared__ float red[4];
    const int lane = threadIdx.x & 63, wave = threadIdx.x >> 6;
    if (lane == 0) red[wave] = s;
    __syncthreads();
    if (threadIdx.x == 0) rden[t] = 1.0f / (red[0] + red[1] + red[2] + red[3]);
}

// ---------------- K3: Y = (A @ V) * rden, ragged K, 128x128 blocks ----------------
__global__ __launch_bounds__(256, 3) void k3_out(const unsigned short* __restrict__ Am,
                                                 const unsigned short* __restrict__ vT,
                                                 const float* __restrict__ rden,
                                                 float* __restrict__ out) {
    extern __shared__ __align__(16) char lds[];
    const int bid = blockIdx.x;
    const int bi = (bid < 256) ? (31 - (bid >> 4)) : ((bid - 256) >> 4);
    const int bj = bid & 15;
    f32x4 acc[4][4];
    pipe_gemm<128, 128, 4, 4>(Am, Tdim, vT, Tdim, bi*128, bj*128, (bi + 1) * 4, lds, acc);
    const int lane = threadIdx.x & 63, wave = threadIdx.x >> 6;
    const int wr = wave >> 1, wc = wave & 1;
    const int er = (lane >> 4) * 4, ec = lane & 15;
    #pragma unroll
    for (int n = 0; n < 4; ++n) {
        const int c = bj*128 + wc*64 + n*16 + ec;
        #pragma unroll
        for (int m = 0; m < 4; ++m)
            #pragma unroll
            for (int jj = 0; jj < 4; ++jj) {
                const int t = bi*128 + wr*64 + m*16 + er + jj;
                out[(size_t)t * Ddim + c] = acc[m][n][jj] * rden[t];
            }
    }
}

// ---------------- launch ----------------
extern "C" void kernel_launch(void* const* d_in, const int* in_sizes, int n_in,
                              void* d_out, int out_size, void* d_ws, size_t ws_size,
                              hipStream_t stream) {
    const float* x  = (const float*)d_in[0];
    const float* Wq = (const float*)d_in[1];
    const float* Wk = (const float*)d_in[2];
    const float* Wv = (const float*)d_in[3];
    char* ws = (char*)d_ws;
    unsigned short* xb   = (unsigned short*)(ws + 0);
    unsigned short* Wb   = (unsigned short*)(ws + (size_t)16777216);
    unsigned short* qkv  = (unsigned short*)(ws + (size_t)41943040);
    unsigned short* vT   = (unsigned short*)(ws + (size_t)92274688);
    unsigned short* Am   = (unsigned short*)(ws + 0);
    float*          rden = (float*)(ws + (size_t)109051904);
    float* out = (float*)d_out;

    (void)hipFuncSetAttribute((const void*)k1_proj, hipFuncAttributeMaxDynamicSharedMemorySize, LDS_K1);

    cvt_all <<<2048, 256, 0, stream>>>(x, Wq, Wk, Wv, xb, Wb);
    k1_proj <<<dim3(N1/256, Tdim/256), 512, LDS_K1, stream>>>(xb, Wb, qkv);
    k1b_trans<<<dim3(Ddim/64, Tdim/64), 256, 0, stream>>>(qkv, vT);
    k2_qk   <<<dim3(528), 256, LDS_K2, stream>>>(qkv, Am);
    k2b_den <<<dim3(Tdim), 256, 0, stream>>>(Am, rden);
    k3_out  <<<dim3(512), 256, LDS_K2, stream>>>(Am, vT, rden, out);
}

// Round 8
// 253.648 us; speedup vs baseline: 1.1198x; 1.1198x over previous
//
#include <hip/hip_runtime.h>
#include <hip/hip_bf16.h>
#include <cstdint>
#include <cstddef>

using bf16x8 = __attribute__((ext_vector_type(8))) short;
using f32x4  = __attribute__((ext_vector_type(4))) float;

#define GAS __attribute__((address_space(1)))
#define LAS __attribute__((address_space(3)))

static constexpr int Tdim = 4096;
static constexpr int Ddim = 2048;
static constexpr int N1   = 6144;   // 3*Ddim

__device__ __forceinline__ unsigned short f32_to_bf16(float f) {
    union { float f; unsigned u; } v; v.f = f;
    return (unsigned short)((v.u + 0x7FFFu + ((v.u >> 16) & 1u)) >> 16);
}
__device__ __forceinline__ float bflo(unsigned u){ union{unsigned x;float f;}v; v.x = u << 16;        return v.f; }
__device__ __forceinline__ float bfhi(unsigned u){ union{unsigned x;float f;}v; v.x = u & 0xFFFF0000u; return v.f; }

// ---------------- fused f32 -> bf16 conversion for x, Wq, Wk, Wv ----------------
__global__ __launch_bounds__(256) void cvt_all(const float* __restrict__ x,
                                               const float* __restrict__ Wq,
                                               const float* __restrict__ Wk,
                                               const float* __restrict__ Wv,
                                               unsigned short* __restrict__ xb,
                                               unsigned short* __restrict__ Wb) {
    constexpr int NX = (Tdim * Ddim) / 4;
    constexpr int NWm = (Ddim * Ddim) / 4;
    const int i0 = blockIdx.x * blockDim.x + threadIdx.x;
    const int stride = gridDim.x * blockDim.x;
    for (int i = i0; i < NX + 3 * NWm; i += stride) {
        const float* s; unsigned short* d; int j;
        if (i < NX)            { s = x;  d = xb;                            j = i; }
        else if (i < NX+NWm)   { s = Wq; d = Wb;                            j = i - NX; }
        else if (i < NX+2*NWm) { s = Wk; d = Wb + (size_t)Ddim*Ddim;        j = i - NX - NWm; }
        else                   { s = Wv; d = Wb + 2*(size_t)Ddim*Ddim;      j = i - NX - 2*NWm; }
        float4 f = ((const float4*)s)[j];
        ushort4 o;
        o.x = f32_to_bf16(f.x); o.y = f32_to_bf16(f.y);
        o.z = f32_to_bf16(f.z); o.w = f32_to_bf16(f.w);
        ((ushort4*)d)[j] = o;
    }
}

__device__ __forceinline__ void gload16(const void* g, void* l) {
    __builtin_amdgcn_global_load_lds((GAS void*)g, (LAS void*)l, 16, 0, 0);
}

// T2 swizzle for 64B-stride rows (involution on byte bits [5:4]): 16 consecutive
// rows x 4 slots -> 8 bank-groups x 2 lanes = conflict-free (verified 0 in R2-R7).
__device__ __forceinline__ int swz(int r) { return ((r >> 1) & 3) << 4; }

// ============ proven 2-phase ring-3 pipeline (R3 structure) ============
// C[TBM x TBN] = A[row0..+TBM, K] * B[col0..+TBN, K]^T ; bf16 row-major.
// NW waves in (TBM/(MR*16)) x (TBN/64) grid; wave-tile (MR*16) x 64.
// Ring-3 LDS, stage-ahead-2, counted vmcnt (never 0 mid-loop).
template<int TBM, int TBN, int NW, int MR>
__device__ __forceinline__ void pipe_gemm(const unsigned short* __restrict__ Ag, int lda,
                                          const unsigned short* __restrict__ Bg, int ldb,
                                          int row0, int col0, int nt,
                                          char* lds, f32x4 acc[MR][4]) {
    constexpr int WCOL   = TBN / 64;
    constexpr int ISSUES = (TBM + TBN) / (NW * 16);
    constexpr int BUF    = (TBM + TBN) * 64;
    const int tid = threadIdx.x, wave = tid >> 6, lane = tid & 63;
    const int wr = wave / WCOL, wc = wave % WCOL;

    // staging: LDS-linear gangs (DMA constraint), global src pre-swizzled (rule 21)
    const char* gp[ISSUES]; int lo[ISSUES];
    #pragma unroll
    for (int i = 0; i < ISSUES; ++i) {
        int o = i * (NW * 1024) + wave * 1024 + (lane << 4);
        lo[i] = i * (NW * 1024) + wave * 1024;
        if (o < TBM * 64) {
            int r = o >> 6, cp = o & 63;
            gp[i] = (const char*)Ag + (size_t)(row0 + r) * (size_t)lda * 2 + (cp ^ swz(r));
        } else {
            int o2 = o - TBM * 64; int r = o2 >> 6, cp = o2 & 63;
            gp[i] = (const char*)Bg + (size_t)(col0 + r) * (size_t)ldb * 2 + (cp ^ swz(r));
        }
    }
    const int fr = lane & 15, fkB = (lane >> 4) << 4;
    int offA[MR], offB[4];
    #pragma unroll
    for (int m = 0; m < MR; ++m) { int r = wr*(MR*16) + m*16 + fr; offA[m] = r*64 + (fkB ^ swz(r)); }
    #pragma unroll
    for (int n = 0; n < 4; ++n)  { int r = wc*64 + n*16 + fr; offB[n] = TBM*64 + r*64 + (fkB ^ swz(r)); }

    #pragma unroll
    for (int m = 0; m < MR; ++m)
        #pragma unroll
        for (int n = 0; n < 4; ++n)
            #pragma unroll
            for (int q = 0; q < 4; ++q) acc[m][n][q] = 0.0f;

    #pragma unroll
    for (int tt = 0; tt < 2; ++tt) {
        char* dst = lds + tt * BUF;
        #pragma unroll
        for (int i = 0; i < ISSUES; ++i) gload16(gp[i] + (size_t)tt * 64, dst + lo[i]);
    }
    asm volatile("s_waitcnt vmcnt(%0)" :: "n"(ISSUES) : "memory");
    __builtin_amdgcn_s_barrier();
    __builtin_amdgcn_sched_barrier(0);

    int cur = 0, stg = 2 * BUF;
    for (int t = 0; t < nt; ++t) {
        const char* buf = lds + cur;
        bf16x8 af[MR], bq[4];
        #pragma unroll
        for (int m = 0; m < MR; ++m) af[m] = *(const bf16x8*)(buf + offA[m]);
        #pragma unroll
        for (int n = 0; n < 4; ++n) bq[n] = *(const bf16x8*)(buf + offB[n]);
        if (t + 2 < nt) {
            char* dst = lds + stg;
            const size_t ko = (size_t)(t + 2) * 64;
            #pragma unroll
            for (int i = 0; i < ISSUES; ++i) gload16(gp[i] + ko, dst + lo[i]);
        }
        __builtin_amdgcn_s_setprio(1);
        #pragma unroll
        for (int m = 0; m < MR; ++m)
            #pragma unroll
            for (int n = 0; n < 4; ++n)
                acc[m][n] = __builtin_amdgcn_mfma_f32_16x16x32_bf16(af[m], bq[n], acc[m][n], 0, 0, 0);
        __builtin_amdgcn_s_setprio(0);
        __builtin_amdgcn_sched_barrier(0);
        if (t + 1 < nt) {
            if (t + 3 <= nt) asm volatile("s_waitcnt vmcnt(%0)" :: "n"(ISSUES) : "memory");
            else             asm volatile("s_waitcnt vmcnt(0)" ::: "memory");
            __builtin_amdgcn_s_barrier();
            __builtin_amdgcn_sched_barrier(0);
        }
        cur = (cur == 2*BUF) ? 0 : cur + BUF;
        stg = (stg == 2*BUF) ? 0 : stg + BUF;
    }
}

static constexpr int LDS_K1 = 3 * (128 + 256) * 64;  // 73728 B -> 2 blocks/CU
static constexpr int LDS_K2 = 3 * (128 + 128) * 64;  // 49152 B -> 3 blocks/CU

// ---------------- K1: fused QKV projection + sigmoid epilogue ----------------
// R3-proven: 128x256 tile, 8 waves (2x4), wave-tile 64x64, natural bj-fastest grid.
__global__ __launch_bounds__(512, 4) void k1_proj(const unsigned short* __restrict__ xb,
                                                  const unsigned short* __restrict__ Wb,
                                                  unsigned short* __restrict__ qkv) {
    extern __shared__ __align__(16) char lds[];
    const int bi = blockIdx.y, bj = blockIdx.x;
    f32x4 acc[4][4];
    pipe_gemm<128, 256, 8, 4>(xb, Ddim, Wb, Ddim, bi*128, bj*256, Ddim/32, lds, acc);
    const int lane = threadIdx.x & 63, wave = threadIdx.x >> 6;
    const int wr = wave >> 2, wc = wave & 3;
    const int er = (lane >> 4) * 4, ec = lane & 15;
    #pragma unroll
    for (int n = 0; n < 4; ++n) {
        const int c = bj*256 + wc*64 + n*16 + ec;
        const bool isQK = (c < 2*Ddim);
        const int ihalf = (c & (Ddim-1)) >> 1;
        float theta = 0.0f;
        if (isQK && ihalf < 2) theta = powf(10000.0f, -2.0f*(float)ihalf);
        #pragma unroll
        for (int m = 0; m < 4; ++m) {
            #pragma unroll
            for (int jj = 0; jj < 4; ++jj) {
                const int t = bi*128 + wr*64 + m*16 + er + jj;
                float v = acc[m][n][jj];
                float ov;
                if (isQK) {
                    float cs = 1.0f;  // exact for ihalf>=2 (ang<=4e-13 -> cos+sin==1.0f)
                    if (ihalf < 2) { float ang = (float)t * theta; cs = cosf(ang) + sinf(ang); }
                    float z = v * cs * (1.0f/2048.0f);
                    ov = 1.0f / (1.0f + expf(-z));
                } else {
                    ov = v;
                }
                qkv[(size_t)t * N1 + c] = f32_to_bf16(ov);
            }
        }
    }
}

// ---------------- K1b: transpose V -> vT [2048][4096] ----------------
__global__ __launch_bounds__(256) void k1b_trans(const unsigned short* __restrict__ qkv,
                                                 unsigned short* __restrict__ vT) {
    __shared__ unsigned short tile[64][65];
    const int tc = blockIdx.x, tr = blockIdx.y;
    const int x = threadIdx.x & 63, y0 = threadIdx.x >> 6;
    #pragma unroll
    for (int r = 0; r < 64; r += 4) {
        const int row = r + y0;
        tile[row][x] = qkv[(size_t)(tr*64 + row) * N1 + 2*Ddim + tc*64 + x];
    }
    __syncthreads();
    #pragma unroll
    for (int r = 0; r < 64; r += 4) {
        const int row = r + y0;
        vT[(size_t)(tc*64 + row) * Tdim + tr*64 + x] = tile[x][row];
    }
}

// ---------------- K2: A = query @ key^T, lower-tri 128x128 blocks (528) ----------------
// Natural block order (no XCD swizzle): R6/R7 showed chunked swizzle thrashes L2.
__global__ __launch_bounds__(256, 3) void k2_qk(const unsigned short* __restrict__ qkv,
                                                unsigned short* __restrict__ Am) {
    extern __shared__ __align__(16) char lds[];
    const int p = blockIdx.x;
    int bi = (int)((sqrtf(8.0f*(float)p + 1.0f) - 1.0f) * 0.5f);
    while ((bi+1)*(bi+2)/2 <= p) ++bi;
    while (bi*(bi+1)/2 > p) --bi;
    const int bj = p - bi*(bi+1)/2;
    f32x4 acc[4][4];
    pipe_gemm<128, 128, 4, 4>(qkv, N1, qkv + Ddim, N1, bi*128, bj*128, Ddim/32, lds, acc);
    const int lane = threadIdx.x & 63, wave = threadIdx.x >> 6;
    const int wr = wave >> 1, wc = wave & 1;
    const int er = (lane >> 4) * 4, ec = lane & 15;
    #pragma unroll
    for (int n = 0; n < 4; ++n) {
        const int s = bj*128 + wc*64 + n*16 + ec;
        #pragma unroll
        for (int m = 0; m < 4; ++m)
            #pragma unroll
            for (int jj = 0; jj < 4; ++jj) {
                const int t = bi*128 + wr*64 + m*16 + er + jj;
                float v = (s <= t) ? acc[m][n][jj] : 0.0f;
                Am[(size_t)t * Tdim + s] = f32_to_bf16(v);
            }
    }
}

// ---------------- K2b: rden[t] = 1 / sum_{s<=t} A[t][s] ----------------
__global__ __launch_bounds__(256) void k2b_den(const unsigned short* __restrict__ Am,
                                               float* __restrict__ rden) {
    const int t = blockIdx.x;
    const int lim = ((t >> 7) + 1) << 7;
    const unsigned short* row = Am + (size_t)t * Tdim;
    float s = 0.0f;
    for (int idx = threadIdx.x * 8; idx < lim; idx += 2048) {
        uint4 u = *(const uint4*)(row + idx);
        s += bflo(u.x) + bfhi(u.x) + bflo(u.y) + bfhi(u.y)
           + bflo(u.z) + bfhi(u.z) + bflo(u.w) + bfhi(u.w);
    }
    #pragma unroll
    for (int off = 32; off > 0; off >>= 1) s += __shfl_down(s, off, 64);
    __shared__ float red[4];
    const int lane = threadIdx.x & 63, wave = threadIdx.x >> 6;
    if (lane == 0) red[wave] = s;
    __syncthreads();
    if (threadIdx.x == 0) rden[t] = 1.0f / (red[0] + red[1] + red[2] + red[3]);
}

// ---------------- K3: Y = (A @ V) * rden, ragged K, 128x128 blocks ----------------
// Long/short pairing: bid<256 -> bi = 31-(bid>>4) (long), bid>=256 -> bi = (bid-256)>>4.
__global__ __launch_bounds__(256, 3) void k3_out(const unsigned short* __restrict__ Am,
                                                 const unsigned short* __restrict__ vT,
                                                 const float* __restrict__ rden,
                                                 float* __restrict__ out) {
    extern __shared__ __align__(16) char lds[];
    const int bid = blockIdx.x;
    const int bi = (bid < 256) ? (31 - (bid >> 4)) : ((bid - 256) >> 4);
    const int bj = bid & 15;
    f32x4 acc[4][4];
    pipe_gemm<128, 128, 4, 4>(Am, Tdim, vT, Tdim, bi*128, bj*128, (bi + 1) * 4, lds, acc);
    const int lane = threadIdx.x & 63, wave = threadIdx.x >> 6;
    const int wr = wave >> 1, wc = wave & 1;
    const int er = (lane >> 4) * 4, ec = lane & 15;
    #pragma unroll
    for (int n = 0; n < 4; ++n) {
        const int c = bj*128 + wc*64 + n*16 + ec;
        #pragma unroll
        for (int m = 0; m < 4; ++m)
            #pragma unroll
            for (int jj = 0; jj < 4; ++jj) {
                const int t = bi*128 + wr*64 + m*16 + er + jj;
                out[(size_t)t * Ddim + c] = acc[m][n][jj] * rden[t];
            }
    }
}

// ---------------- launch ----------------
extern "C" void kernel_launch(void* const* d_in, const int* in_sizes, int n_in,
                              void* d_out, int out_size, void* d_ws, size_t ws_size,
                              hipStream_t stream) {
    const float* x  = (const float*)d_in[0];
    const float* Wq = (const float*)d_in[1];
    const float* Wk = (const float*)d_in[2];
    const float* Wv = (const float*)d_in[3];
    char* ws = (char*)d_ws;
    unsigned short* xb   = (unsigned short*)(ws + 0);
    unsigned short* Wb   = (unsigned short*)(ws + (size_t)16777216);
    unsigned short* qkv  = (unsigned short*)(ws + (size_t)41943040);
    unsigned short* vT   = (unsigned short*)(ws + (size_t)92274688);
    unsigned short* Am   = (unsigned short*)(ws + 0);
    float*          rden = (float*)(ws + (size_t)109051904);
    float* out = (float*)d_out;

    (void)hipFuncSetAttribute((const void*)k1_proj, hipFuncAttributeMaxDynamicSharedMemorySize, LDS_K1);

    cvt_all <<<2048, 256, 0, stream>>>(x, Wq, Wk, Wv, xb, Wb);
    k1_proj <<<dim3(N1/256, Tdim/128), 512, LDS_K1, stream>>>(xb, Wb, qkv);
    k1b_trans<<<dim3(Ddim/64, Tdim/64), 256, 0, stream>>>(qkv, vT);
    k2_qk   <<<dim3(528), 256, LDS_K2, stream>>>(qkv, Am);
    k2b_den <<<dim3(Tdim), 256, 0, stream>>>(Am, rden);
    k3_out  <<<dim3(512), 256, LDS_K2, stream>>>(Am, vT, rden, out);
}